// Round 3
// baseline (57.383 us; speedup 1.0000x reference)
//
#include <hip/hip_runtime.h>
#include <math.h>

#define BATCH 128
#define NPWM 512
#define LEN 1000
#define KSZ 19
#define NPOS 982
#define NEXT 1024     // 2*NPWM (fwd + revcomp interleaved: f_ext = 2*f + strand)
#define KSLOT 96      // kk padded 19->24, slot = kk*4 + c

// LDS element offsets: shifted copies at +4128 (= +4096 + 32) so odd-parity
// lanes' bank groups are offset by 4 (mod 8) vs even-parity lanes -> max 3-way.
#define H0_OFF 0
#define H1_OFF 4128
#define L0_OFF 8256
#define L1_OFF 12384
#define S_ELEMS 16480

typedef __bf16 bf16x8 __attribute__((ext_vector_type(8)));
typedef float  f32x4  __attribute__((ext_vector_type(4)));

#define MFMA(a, b, c) __builtin_amdgcn_mfma_f32_16x16x32_bf16(a, b, c, 0, 0, 0)

// ---- prepack W: (512,4,19) fp32 -> (1024,96) bf16 hi/lo, zeros at pad slots ----
__global__ __launch_bounds__(256)
void prepack_w(const float* __restrict__ w, __bf16* __restrict__ whi, __bf16* __restrict__ wlo)
{
    int idx = blockIdx.x * 256 + threadIdx.x;
    if (idx >= NEXT * KSLOT) return;
    int fe = idx / KSLOT;
    int t  = idx - fe * KSLOT;
    int kk = t >> 2;
    int c  = t & 3;
    int f      = fe >> 1;
    int strand = fe & 1;
    float v = 0.0f;
    if (kk < KSZ)
        v = strand ? w[f*76 + (3-c)*19 + (18-kk)]   // reverse-complement
                   : w[f*76 + c*19 + kk];
    __bf16 h = (__bf16)v;
    whi[idx] = h;
    wlo[idx] = (__bf16)(v - (float)h);
}

// ---- main: im2col bf16-split MFMA GEMM + fused position-max ----
// block = 256 thr = 4 waves = 2 filter-halves x 2 position-halves.
// Per wave: 64 f_ext (fg=4), ~15.5 K-iters, 12 LDS B-reads : 72 MFMA per iter.
__global__ __launch_bounds__(256)
void pwm_mfma(const float* __restrict__ x,
              const __bf16* __restrict__ whi,
              const __bf16* __restrict__ wlo,
              float* __restrict__ out)
{
    __shared__ __align__(16) __bf16 S[S_ELEMS];
    __shared__ float red[2][128];

    const int tid   = threadIdx.x;
    const int b     = blockIdx.x;
    const int ftile = blockIdx.y;   // 0..7
    const int lane  = tid & 63;
    const int wave  = tid >> 6;
    const int fhalf = wave & 1;     // which 64 f_ext
    const int wp    = wave >> 1;    // which position half

    // stage x[b] -> bf16 hi/lo, position-major [pos][channel]
    for (int i = tid; i < 1024; i += 256) {
        #pragma unroll
        for (int c = 0; c < 4; ++c) {
            float v = (i < LEN) ? x[(size_t)b*4000 + c*1000 + i] : 0.0f;
            __bf16 h = (__bf16)v;
            S[H0_OFF + i*4 + c] = h;
            S[L0_OFF + i*4 + c] = (__bf16)(v - (float)h);
        }
    }
    __syncthreads();
    { // shifted copies (pos+1) for odd-parity lane alignment
        const unsigned long long* s0 = (const unsigned long long*)(S + H0_OFF);
        const unsigned long long* s2 = (const unsigned long long*)(S + L0_OFF);
        unsigned long long* d1 = (unsigned long long*)(S + H1_OFF);
        unsigned long long* d3 = (unsigned long long*)(S + L1_OFF);
        for (int i = tid; i < 1024; i += 256) {
            d1[i] = (i < 1023) ? s0[i+1] : 0ull;
            d3[i] = (i < 1023) ? s2[i+1] : 0ull;
        }
    }

    const int row = lane & 15;
    const int g   = lane >> 4;

    // A fragments (W) -> registers: lane holds W[f0+fg*16+row][k = s*32 + g*8 + j]
    bf16x8 wah[4][3], wal[4][3];
    {
        const int f0 = ftile*128 + fhalf*64;
        #pragma unroll
        for (int fg = 0; fg < 4; ++fg) {
            const __bf16* ph = whi + (size_t)(f0 + fg*16 + row)*KSLOT + g*8;
            const __bf16* pl = wlo + (size_t)(f0 + fg*16 + row)*KSLOT + g*8;
            #pragma unroll
            for (int s = 0; s < 3; ++s) {
                wah[fg][s] = *(const bf16x8*)(ph + s*32);
                wal[fg][s] = *(const bf16x8*)(pl + s*32);
            }
        }
    }
    __syncthreads();

    // B: pos = it*32 + tile*16 + row; lane's 16B read covers k-slots g*8..g*8+7
    const int lp   = row + 2*g;
    const int par  = row & 1;                  // loop-invariant parity
    const __bf16* bhi = S + (par ? H1_OFF : H0_OFF);
    const __bf16* blo = S + (par ? L1_OFF : L0_OFF);
    const int eoff = lp*4 - (par ? 4 : 0);

    float m[4][4];
    #pragma unroll
    for (int fg = 0; fg < 4; ++fg)
        #pragma unroll
        for (int r = 0; r < 4; ++r) m[fg][r] = -INFINITY;

    const int it_beg = wp * 16;
    const int it_end = wp ? 31 : 16;
    for (int it = it_beg; it < it_end; ++it) {
        f32x4 acc0[4], acc1[4];
        #pragma unroll
        for (int fg = 0; fg < 4; ++fg) {
            acc0[fg] = (f32x4){0,0,0,0};
            acc1[fg] = (f32x4){0,0,0,0};
        }
        const int ibase = it*128 + eoff;
        #pragma unroll
        for (int s = 0; s < 3; ++s) {
            bf16x8 bh0 = *(const bf16x8*)(bhi + ibase + s*32);
            bf16x8 bl0 = *(const bf16x8*)(blo + ibase + s*32);
            bf16x8 bh1 = *(const bf16x8*)(bhi + ibase + 64 + s*32);
            bf16x8 bl1 = *(const bf16x8*)(blo + ibase + 64 + s*32);
            #pragma unroll
            for (int fg = 0; fg < 4; ++fg) {
                acc0[fg] = MFMA(wah[fg][s], bh0, acc0[fg]);
                acc0[fg] = MFMA(wah[fg][s], bl0, acc0[fg]);
                acc0[fg] = MFMA(wal[fg][s], bh0, acc0[fg]);
                acc1[fg] = MFMA(wah[fg][s], bh1, acc1[fg]);
                acc1[fg] = MFMA(wah[fg][s], bl1, acc1[fg]);
                acc1[fg] = MFMA(wal[fg][s], bh1, acc1[fg]);
            }
        }
        if (it == 30 && row >= 6) {   // mask positions >= 982 (D col = 976+row)
            #pragma unroll
            for (int fg = 0; fg < 4; ++fg)
                #pragma unroll
                for (int r = 0; r < 4; ++r) acc1[fg][r] = -INFINITY;
        }
        #pragma unroll
        for (int fg = 0; fg < 4; ++fg)
            #pragma unroll
            for (int r = 0; r < 4; ++r)
                m[fg][r] = fmaxf(m[fg][r], fmaxf(acc0[fg][r], acc1[fg][r]));
    }

    // reduce over the 16 position-columns (lane&15)
    #pragma unroll
    for (int off = 1; off < 16; off <<= 1)
        #pragma unroll
        for (int fg = 0; fg < 4; ++fg)
            #pragma unroll
            for (int r = 0; r < 4; ++r)
                m[fg][r] = fmaxf(m[fg][r], __shfl_xor(m[fg][r], off, 64));

    if (row == 0) {
        #pragma unroll
        for (int fg = 0; fg < 4; ++fg)
            #pragma unroll
            for (int r = 0; r < 4; ++r)
                red[wp][fhalf*64 + fg*16 + g*4 + r] = m[fg][r];
    }
    __syncthreads();
    if (tid < 64) {   // combine strands (f_ext = 2f, 2f+1) and position halves
        float a = fmaxf(red[0][2*tid], red[0][2*tid+1]);
        float c = fmaxf(red[1][2*tid], red[1][2*tid+1]);
        out[(size_t)b*NPWM + ftile*64 + tid] = fmaxf(a, c);
    }
}

extern "C" void kernel_launch(void* const* d_in, const int* in_sizes, int n_in,
                              void* d_out, int out_size, void* d_ws, size_t ws_size,
                              hipStream_t stream)
{
    const float* x = (const float*)d_in[0];   // (128, 4, 1000)
    const float* w = (const float*)d_in[1];   // (512, 4, 19)
    float* out = (float*)d_out;               // (128, 512)

    __bf16* whi = (__bf16*)d_ws;              // 1024*96 bf16
    __bf16* wlo = whi + NEXT*KSLOT;

    prepack_w<<<dim3((NEXT*KSLOT + 255)/256), 256, 0, stream>>>(w, whi, wlo);
    pwm_mfma<<<dim3(BATCH, 8), 256, 0, stream>>>(x, whi, wlo, out);
}